// Round 6
// baseline (801.725 us; speedup 1.0000x reference)
//
#include <hip/hip_runtime.h>
#include <hip/hip_bf16.h>

#define NN 768
#define NE 24576
#define NPOS 4096
#define NCELL (NN*NN)   // 589824 = 2304*256
#define NBKT 3072       // (row, quarter) buckets
#define QW 192          // quarter width

typedef __hip_bfloat16 bf16;

__device__ __forceinline__ float ldf(const void* p, int i, int mode) {
    return mode ? __bfloat162float(((const bf16*)p)[i]) : ((const float*)p)[i];
}
__device__ __forceinline__ float aread(float* p) { return atomicAdd(p, 0.f); }
__device__ __forceinline__ int areadi(int* p) { return atomicAdd(p, 0); }

// ---------------- setup: clear cell/aux, detect dtype, convert weights ----------------
__global__ void k_setup(const void* __restrict__ gW, const void* __restrict__ gB,
                        const void* __restrict__ m1W, const void* __restrict__ m1B,
                        const void* __restrict__ m2W, const void* __restrict__ m2B,
                        const void* __restrict__ m3W, const void* __restrict__ m3B,
                        const void* __restrict__ lW,  const void* __restrict__ lB,
                        const void* __restrict__ emb,
                        int* __restrict__ cell, float* __restrict__ stats,
                        int* __restrict__ cursor, int* __restrict__ rowq,
                        int* __restrict__ bcnt, int* __restrict__ cur,
                        int* __restrict__ dcs, int* __restrict__ modeg,
                        float* __restrict__ gwf, float* __restrict__ gbf,
                        float* __restrict__ w1f, float* __restrict__ b1f,
                        float* __restrict__ w2f, float* __restrict__ b2f,
                        float* __restrict__ w3q, float* __restrict__ linf, float* __restrict__ linb) {
    int t = threadIdx.x;
    int b = blockIdx.x;
    if (b < NCELL / 256) { cell[b * 256 + t] = 0; return; }
    if (b == NCELL / 256 + 1) {
        for (int i = t; i < NN; i += 256) cursor[i] = 0;
        for (int i = t; i < NN * 4; i += 256) rowq[i] = 0;
        for (int i = t; i < NBKT; i += 256) { bcnt[i] = 0; cur[i] = 0; }
        if (t < 66) stats[t] = 0.f;
        if (t < 8) dcs[t] = 0;
        return;
    }
    __shared__ int bad;
    if (t == 0) bad = 0;
    __syncthreads();
    int local = 0;
    for (int i = t; i < 3232; i += 256) {
        float a = fabsf(__bfloat162float(((const bf16*)emb)[i]));
        if (!(a < 100.f)) local = 1;
    }
    if (local) atomicOr(&bad, 1);
    __syncthreads();
    int mode = bad ? 0 : 1;
    if (t == 0) *modeg = mode;
    for (int i = t; i < 2048; i += 256) {
        gwf[i] = ldf(gW, i, mode);
        w1f[i] = ldf(m1W, i, mode);
        w2f[i] = ldf(m2W, i, mode);
    }
    for (int i = t; i < 64; i += 256) { gbf[i] = ldf(gB, i, mode); linf[i] = ldf(lW, i, mode); }
    if (t < 32) { b1f[t] = ldf(m1B, t, mode); b2f[t] = ldf(m2B, t, mode); }
    // w3q row d (stride 36 floats = 144 B, 16B-aligned): [W3[0..31][d], ind, b3, 0, 0]
    for (int i = t; i < 1056; i += 256) { int c = i >> 5, d = i & 31; w3q[d * 36 + c] = ldf(m3W, i, mode); }
    if (t < 32) { w3q[t * 36 + 33] = ldf(m3B, t, mode); w3q[t * 36 + 34] = 0.f; w3q[t * 36 + 35] = 0.f; }
    if (t == 0) linb[0] = ldf(lB, 0, mode);
}

// ---------------- edge scatter + rowq first-touch; last block: row_ptr scan + dinv ----------------
__global__ void k_scatter(const int* __restrict__ ei, int* __restrict__ cell, int* __restrict__ rowq,
                          int* __restrict__ row_ptr, float* __restrict__ dinv, int* __restrict__ dc) {
    int t = threadIdx.x;
    int e = blockIdx.x * 256 + t;
    int a = ei[e], b = ei[NE + e];
    if ((unsigned)a < (unsigned)NN && (unsigned)b < (unsigned)NN) {
        int old = atomicAdd(&cell[a * NN + b], 1);
        if (old == 0) atomicAdd(&rowq[a * 4 + b / QW], 1);
    }
    __syncthreads();
    __shared__ int amlast;
    if (t == 0) { __threadfence(); amlast = (atomicAdd(dc, 1) == 95) ? 1 : 0; }
    __syncthreads();
    if (!amlast) return;
    __shared__ int sr[NN];
    __shared__ int sp[NN + 1];
    for (int i = t; i < NN; i += 256) {
        int rl = 0;
        for (int q = 0; q < 4; q++) rl += areadi(&rowq[i * 4 + q]);
        sr[i] = rl;
        dinv[i] = rsqrtf((float)rl + 1.0f);
    }
    __syncthreads();
    if (t == 0) {
        int acc = 0;
        for (int i = 0; i < NN; i++) { sp[i] = acc; acc += sr[i]; }
        sp[NN] = acc;
    }
    __syncthreads();
    for (int i = t; i <= NN; i += 256) row_ptr[i] = sp[i];
}

// ---------------- fillpar(2304) + matw0(96); last block: bptr scan ----------------
__global__ void k_fillmat(int* __restrict__ cell, const int* __restrict__ row_ptr, int* __restrict__ cursor,
                          int* __restrict__ col_idx, float* __restrict__ cntv, int* __restrict__ pr_row,
                          const int* __restrict__ rowq, int* __restrict__ bcnt,
                          const int* __restrict__ x, const void* __restrict__ emb,
                          const int* __restrict__ modep, const float* __restrict__ gwf,
                          float* __restrict__ bufA,
                          int* __restrict__ bptr, int* __restrict__ dc) {
    int t = threadIdx.x;
    int b = blockIdx.x;
    if (b < NCELL / 256) {
        int idx = b * 256 + t;
        int i = idx / NN;
        int j = idx - i * NN;
        int cv = cell[idx];
        if (cv > 0) {
            int p = row_ptr[i] + atomicAdd(&cursor[i], 1);
            col_idx[p] = j; cntv[p] = (float)cv; pr_row[p] = i;
            cell[idx] = p;
            for (int q = 0; q < 4; q++) {
                int rq = rowq[j * 4 + q];
                if (rq) atomicAdd(&bcnt[i * 4 + q], rq);
            }
        } else {
            cell[idx] = -1;
        }
    } else {
        int idx = (b - NCELL / 256) * 256 + t;  // 768*32
        int i = idx >> 5, d = idx & 31;
        int mode = *modep;
        int xi = x[i];
        if (xi < 0) xi = 0; if (xi > 100) xi = 100;
        float s = 0.f;
#pragma unroll
        for (int c = 0; c < 32; c++) s += ldf(emb, xi * 32 + c, mode) * gwf[c * 32 + d];
        bufA[idx] = s;
    }
    __syncthreads();
    __shared__ int amlast;
    if (t == 0) { __threadfence(); amlast = (atomicAdd(dc, 1) == NCELL / 256 + 96 - 1) ? 1 : 0; }
    __syncthreads();
    if (!amlast) return;
    __shared__ int sb[NBKT];
    __shared__ int tot;
    for (int q = t; q < NBKT; q += 256) sb[q] = areadi(&bcnt[q]);
    __syncthreads();
    if (t == 0) {
        int acc = 0;
        for (int q = 0; q < NBKT; q++) { int v = sb[q]; sb[q] = acc; acc += v; }
        tot = acc;
    }
    __syncthreads();
    for (int q = t; q < NBKT; q += 256) bptr[q] = sb[q];
    if (t == 0) bptr[NBKT] = tot;
}

// ---------------- agg (An @ hw + b) + last-block column stats -> nrm_l ----------------
__global__ void k_aggstats(const float* __restrict__ hw, const int* __restrict__ row_ptr,
                           const int* __restrict__ col_idx, const float* __restrict__ dinv,
                           const float* __restrict__ gbf, int l, float* __restrict__ o,
                           float* __restrict__ nrm_l, int* __restrict__ dc) {
    int t = threadIdx.x;
    int idx = blockIdx.x * 256 + t;
    int i = idx >> 5, d = idx & 31;
    int base = row_ptr[i], len = row_ptr[i + 1] - base;
    float di = dinv[i];
    float acc = di * hw[i * 32 + d];
    for (int e = 0; e < len; e++) {
        int c = col_idx[base + e];
        acc += dinv[c] * hw[c * 32 + d];
    }
    atomicExch(&o[idx], di * acc + gbf[l * 32 + d]);   // coherent write for same-dispatch read
    __syncthreads();
    __shared__ int amlast;
    if (t == 0) { __threadfence(); amlast = (atomicAdd(dc, 1) == 95) ? 1 : 0; }
    __syncthreads();
    if (!amlast) return;
    __shared__ float r1[256], r2[256];
    int dd = t & 31, g = t >> 5;
    float s = 0.f, s2 = 0.f;
    for (int r = g; r < NN; r += 8) {
        float v = aread(&o[r * 32 + dd]);
        s += v; s2 += v * v;
    }
    r1[t] = s; r2[t] = s2;
    __syncthreads();
    if (t < 32) {
        float a = 0.f, b2 = 0.f;
        for (int k = 0; k < 8; k++) { a += r1[k * 32 + t]; b2 += r2[k * 32 + t]; }
        float mean = a / (float)NN;
        float var = b2 / (float)NN - mean * mean;
        nrm_l[t] = mean;
        nrm_l[32 + t] = rsqrtf(fmaxf(var, 0.f) + 1e-5f);
    }
}

// ---------------- normalize(bufB, nrm0) -> matw layer 1 -> bufA ----------------
__global__ void k_matw1(const float* __restrict__ bufB, const float* __restrict__ nrm0,
                        const float* __restrict__ gwf, float* __restrict__ bufA) {
    int idx = blockIdx.x * 256 + threadIdx.x;
    int i = idx >> 5, d = idx & 31;
    const float* W = gwf + 1024;
    float s = 0.f;
#pragma unroll
    for (int c = 0; c < 32; c++) {
        float hn = fmaxf((bufB[i * 32 + c] - nrm0[c]) * nrm0[32 + c], 0.f);
        s += hn * W[c * 32 + d];
    }
    bufA[idx] = s;
}

// ---------------- join(96) + edgemlp(3072, inline norm) + hwrite(96) ----------------
__global__ void k_joinedge(const int* __restrict__ row_ptr, const int* __restrict__ col_idx,
                           const int* __restrict__ pr_row, const int* __restrict__ rowq,
                           const int* __restrict__ bptr, int* __restrict__ cur,
                           int2* __restrict__ paths, int cap,
                           const float* __restrict__ bufB, const float* __restrict__ nrm1,
                           const float* __restrict__ cntv,
                           const float* __restrict__ w1f, const float* __restrict__ b1f,
                           const float* __restrict__ w2f, const float* __restrict__ b2f,
                           float* __restrict__ xep, float* __restrict__ mulp,
                           float* __restrict__ h) {
    int t = threadIdx.x;
    int b = blockIdx.x;
    if (b < 96) {
        int e1 = b * 256 + t;
        if (e1 >= row_ptr[NN]) return;
        int i = pr_row[e1], k = col_idx[e1];
        int kb = row_ptr[k], klen = row_ptr[k + 1] - kb;
        int sq[4];
        for (int q = 0; q < 4; q++) {
            int rq = rowq[k * 4 + q];
            sq[q] = bptr[i * 4 + q] + (rq ? atomicAdd(&cur[i * 4 + q], rq) : 0);
        }
        for (int e = 0; e < klen; e++) {
            int e2 = kb + e;
            int j = col_idx[e2];
            int q = j / QW;
            int slot = sq[q]++;
            if (slot < cap) paths[slot] = make_int2(e1 | (j << 16), e2);
        }
        return;
    }
    if (b < 96 + 3072) {
        int d = t & 31;
        int p = (b - 96) * 8 + (t >> 5);
        if (p >= row_ptr[NN]) { if (p < NE) { xep[p * 32 + d] = 0.f; mulp[p * 32 + d] = 0.f; } return; }
        int i = pr_row[p], j = col_idx[p];
        float a1 = b1f[d], a2 = b2f[d];
#pragma unroll
        for (int c = 0; c < 32; c++) {
            float hv = fmaxf((bufB[i * 32 + c] - nrm1[c]) * nrm1[32 + c], 0.f);
            a1 += hv * w1f[c * 32 + d];
            a2 += hv * w2f[c * 32 + d];
        }
#pragma unroll
        for (int c = 0; c < 32; c++) {
            float hv = fmaxf((bufB[j * 32 + c] - nrm1[c]) * nrm1[32 + c], 0.f);
            a1 += hv * w1f[(32 + c) * 32 + d];
            a2 += hv * w2f[(32 + c) * 32 + d];
        }
        float cv = cntv[p];
        xep[p * 32 + d]  = cv * fmaxf(a1, 0.f);
        mulp[p * 32 + d] = cv * fmaxf(a2, 0.f);
        return;
    }
    int idx = (b - 96 - 3072) * 256 + t;
    int d = idx & 31;
    h[idx] = fmaxf((bufB[idx] - nrm1[d]) * nrm1[32 + d], 0.f);
}

// ---------------- fused: path-scatter into LDS C-tile + z + masked stats ----------------
__global__ __launch_bounds__(256) void k_big(const int* __restrict__ bptr, const int2* __restrict__ paths,
                                             const int* __restrict__ cell,
                                             const float* __restrict__ xep, const float* __restrict__ mulp,
                                             const float* __restrict__ w3q,
                                             float* __restrict__ stats, int* __restrict__ done,
                                             float* __restrict__ nrm, int cap) {
    __shared__ float Cs[QW * 32];           // 24 KB, swizzled [jj*32 + ((c+jj)&31)]
    __shared__ float sw3[36 * 32];          // 4.6 KB W3 copy
    __shared__ int   mk[QW];
    __shared__ float sS1[32], sS2[32], sCm[32];
    __shared__ int amlast;
    int t = threadIdx.x, d = t & 31, tt = t >> 5, lane = t & 63;
    int bkt = blockIdx.x;
    int i = bkt >> 2;
    int jbase = (bkt & 3) * QW;
    for (int e = t; e < QW * 32; e += 256) Cs[e] = 0.f;
    for (int e = t; e < 1152; e += 256) sw3[e] = w3q[e];
    for (int e = t; e < QW; e += 256) mk[e] = 0;
    if (t < 32) { sS1[t] = 0.f; sS2[t] = 0.f; sCm[t] = 0.f; }
    __syncthreads();
    // phase A: flat path scatter, 2x unrolled for MLP
    int pstart = bptr[bkt], pend = bptr[bkt + 1];
    if (pend > cap) pend = cap;
    int p = pstart + tt;
    for (; p + 8 < pend; p += 16) {
        int2 r1 = paths[p];
        int2 r2 = paths[p + 8];
        int e1a = r1.x & 0xFFFF, e2a = r1.y, jja = (((unsigned)r1.x) >> 16) - jbase;
        int e1b = r2.x & 0xFFFF, e2b = r2.y, jjb = (((unsigned)r2.x) >> 16) - jbase;
        float xa = xep[e1a * 32 + d], ma = mulp[e2a * 32 + d];
        float xb = xep[e1b * 32 + d], mb = mulp[e2b * 32 + d];
        atomicAdd(&Cs[jja * 32 + ((d + jja) & 31)], xa * ma);
        atomicAdd(&Cs[jjb * 32 + ((d + jjb) & 31)], xb * mb);
        if (d == 0) { mk[jja] = 1; mk[jjb] = 1; }
    }
    if (p < pend) {
        int2 r1 = paths[p];
        int e1a = r1.x & 0xFFFF, e2a = r1.y, jja = (((unsigned)r1.x) >> 16) - jbase;
        float v = xep[e1a * 32 + d] * mulp[e2a * 32 + d];
        atomicAdd(&Cs[jja * 32 + ((d + jja) & 31)], v);
        if (d == 0) mk[jja] = 1;
    }
    __syncthreads();
    // phase B: per-cell z + stats; W3 operands from LDS broadcasts
    float ts1[32], ts2[32];
#pragma unroll
    for (int c = 0; c < 32; c++) { ts1[c] = 0.f; ts2[c] = 0.f; }
    float cm = 0.f;
    if (t < QW) {
        int jj = t;
        float Creg[32];
#pragma unroll
        for (int c = 0; c < 32; c++) Creg[c] = Cs[jj * 32 + ((c + jj) & 31)];
        bool adj = cell[i * NN + jbase + jj] >= 0;
        float af = adj ? 1.f : 0.f;
        float msk = (mk[jj] || adj) ? 1.f : 0.f;
        cm = msk;
#pragma unroll
        for (int dd = 0; dd < 32; dd++) {
            const float4* wr = (const float4*)(sw3 + dd * 36);   // uniform addr -> LDS broadcast
            float4 wv = wr[8];
            float z = wv.y + af * wv.x;
            wv = wr[0]; z += Creg[0]*wv.x + Creg[1]*wv.y + Creg[2]*wv.z + Creg[3]*wv.w;
            wv = wr[1]; z += Creg[4]*wv.x + Creg[5]*wv.y + Creg[6]*wv.z + Creg[7]*wv.w;
            wv = wr[2]; z += Creg[8]*wv.x + Creg[9]*wv.y + Creg[10]*wv.z + Creg[11]*wv.w;
            wv = wr[3]; z += Creg[12]*wv.x + Creg[13]*wv.y + Creg[14]*wv.z + Creg[15]*wv.w;
            wv = wr[4]; z += Creg[16]*wv.x + Creg[17]*wv.y + Creg[18]*wv.z + Creg[19]*wv.w;
            wv = wr[5]; z += Creg[20]*wv.x + Creg[21]*wv.y + Creg[22]*wv.z + Creg[23]*wv.w;
            wv = wr[6]; z += Creg[24]*wv.x + Creg[25]*wv.y + Creg[26]*wv.z + Creg[27]*wv.w;
            wv = wr[7]; z += Creg[28]*wv.x + Creg[29]*wv.y + Creg[30]*wv.z + Creg[31]*wv.w;
            ts1[dd] = msk * z;
            ts2[dd] = msk * z * z;
        }
    }
    // staggered LDS atomics
#pragma unroll
    for (int c = 0; c < 32; c++) {
        int dd = (c + t) & 31;
        atomicAdd(&sS1[dd], ts1[dd]);
        atomicAdd(&sS2[dd], ts2[dd]);
    }
    atomicAdd(&sCm[t & 31], cm);
    __syncthreads();
    if (t < 32) {
        atomicAdd(&stats[t], sS1[t]);
        atomicAdd(&stats[32 + t], sS2[t]);
    }
    if (t == 32) {
        float s = 0.f;
        for (int k = 0; k < 32; k++) s += sCm[k];
        atomicAdd(&stats[64], s);
    }
    __syncthreads();
    if (t == 0) {
        __threadfence();
        amlast = (atomicAdd(done, 1) == NBKT - 1) ? 1 : 0;
    }
    __syncthreads();
    if (amlast && t < 32) {
        float sum1 = aread(&stats[t]);
        float sum2 = aread(&stats[32 + t]);
        float cmv  = aread(&stats[64]);
        if (cmv < 1.f) cmv = 1.f;
        float mean = sum1 / cmv;
        float var = sum2 / cmv - mean * mean;
        nrm[t] = mean;
        nrm[32 + t] = rsqrtf(fmaxf(var, 0.f) + 1e-5f);
    }
}

// ---------------- output: recompute C at pos pairs, norm, sym, linear ----------------
__global__ void k_out(const int* __restrict__ pos, const int* __restrict__ row_ptr,
                      const int* __restrict__ col_idx, const int* __restrict__ cell,
                      const float* __restrict__ xep, const float* __restrict__ mulp,
                      const float* __restrict__ h,
                      const float* __restrict__ w3q,
                      const float* __restrict__ nrm,
                      const float* __restrict__ linf, const float* __restrict__ linb,
                      const int* __restrict__ modep, void* __restrict__ outp) {
    __shared__ float Cb[4][2][32];
    int t = threadIdx.x;
    int w = t >> 6, lane = t & 63, d = lane & 31, dir = lane >> 5;
    int p = blockIdx.x * 4 + w;
    int a = pos[2 * p], b = pos[2 * p + 1];
    if ((unsigned)a >= (unsigned)NN) a = 0;
    if ((unsigned)b >= (unsigned)NN) b = 0;
    int r = dir ? b : a;
    int cc = dir ? a : b;
    int base = row_ptr[r], len = row_ptr[r + 1] - base;
    float acc = 0.f;
    bool hit = false;
    for (int tt = 0; tt < len; tt++) {
        int e1 = base + tt;
        int k = col_idx[e1];
        int e2 = cell[k * NN + cc];
        if (e2 >= 0) { hit = true; acc += xep[e1 * 32 + d] * mulp[e2 * 32 + d]; }
    }
    Cb[w][dir][d] = acc;
    bool adj = cell[r * NN + cc] >= 0;
    float msk = (hit || adj) ? 1.f : 0.f;
    __syncthreads();
    float z = w3q[d * 36 + 33] + (adj ? 1.f : 0.f) * w3q[d * 36 + 32];
#pragma unroll
    for (int c = 0; c < 32; c++) z += Cb[w][dir][c] * w3q[d * 36 + c];
    float zn = fmaxf((z - nrm[d]) * nrm[32 + d], 0.f);
    float zp = __shfl_xor(zn, 32);
    float symd = msk * zn * zp;
    float xxd = h[a * 32 + d] * h[b * 32 + d];
    float contrib = symd * linf[d] + xxd * linf[32 + d];
    for (int off = 16; off >= 1; off >>= 1) contrib += __shfl_xor(contrib, off);
    if (lane == 0) {
        float v = contrib + linb[0];
        v = fminf(fmaxf(v, -1e4f), 1e4f);
        if (*modep) ((bf16*)outp)[p] = __float2bfloat16(v);
        else        ((float*)outp)[p] = v;
    }
}

extern "C" void kernel_launch(void* const* d_in, const int* in_sizes, int n_in,
                              void* d_out, int out_size, void* d_ws, size_t ws_size,
                              hipStream_t stream) {
    const void* px  = d_in[0];  const void* pei = d_in[1];  const void* ppos = d_in[2];
    const void* pemb = d_in[3]; const void* pgW = d_in[4];  const void* pgB  = d_in[5];
    const void* pm1W = d_in[6]; const void* pm1B = d_in[7]; const void* pm2W = d_in[8];
    const void* pm2B = d_in[9]; const void* pm3W = d_in[10]; const void* pm3B = d_in[11];
    const void* plW = d_in[12]; const void* plB = d_in[13];
    {
        int c2048 = 0, c64 = 0, c32 = 0;
        for (int i = 0; i < n_in; i++) {
            int s = in_sizes[i]; const void* p = d_in[i];
            switch (s) {
                case 768:   px = p; break;
                case 49152: pei = p; break;
                case 8192:  ppos = p; break;
                case 3232:  pemb = p; break;
                case 2048:  if (c2048 == 0) pgW = p; else if (c2048 == 1) pm1W = p; else pm2W = p; c2048++; break;
                case 64:    if (c64 == 0) pgB = p; else plW = p; c64++; break;
                case 32:    if (c32 == 0) pm1B = p; else if (c32 == 1) pm2B = p; else pm3B = p; c32++; break;
                case 1056:  pm3W = p; break;
                case 1:     plB = p; break;
                default: break;
            }
        }
    }

    char* ws = (char*)d_ws;
    size_t off = 0;
    auto alloc = [&](size_t bytes) -> void* {
        void* pp = ws + off;
        off += (bytes + 255) & ~(size_t)255;
        return pp;
    };
    int*   cell    = (int*)alloc(NCELL * 4);
    int*   rowq    = (int*)alloc(NN * 4 * 4);
    int*   row_ptr = (int*)alloc((NN + 1) * 4);
    int*   col_idx = (int*)alloc(NE * 4);
    float* cntv    = (float*)alloc(NE * 4);
    int*   pr_row  = (int*)alloc(NE * 4);
    int*   cursor  = (int*)alloc(NN * 4);
    float* dinv    = (float*)alloc(NN * 4);
    float* h       = (float*)alloc(NN * 32 * 4);
    float* bufA    = (float*)alloc(NN * 32 * 4);
    float* bufB    = (float*)alloc(NN * 32 * 4);
    float* xep     = (float*)alloc(NE * 32 * 4);
    float* mulp    = (float*)alloc(NE * 32 * 4);
    float* stats   = (float*)alloc(66 * 4);
    float* nrm     = (float*)alloc(64 * 4);
    float* nrm0    = (float*)alloc(64 * 4);
    float* nrm1    = (float*)alloc(64 * 4);
    float* gwf     = (float*)alloc(2048 * 4);
    float* gbf     = (float*)alloc(64 * 4);
    float* w1f     = (float*)alloc(2048 * 4);
    float* b1f     = (float*)alloc(32 * 4);
    float* w2f     = (float*)alloc(2048 * 4);
    float* b2f     = (float*)alloc(32 * 4);
    float* w3q     = (float*)alloc(32 * 36 * 4);
    float* linf    = (float*)alloc(64 * 4);
    float* linb    = (float*)alloc(4);
    int*   mode    = (int*)alloc(4);
    int*   dcs     = (int*)alloc(8 * 4);     // dc0..dc3, dcB
    int*   bptr    = (int*)alloc((NBKT + 1) * 4);
    int*   bcnt    = (int*)alloc(NBKT * 4);
    int*   cur     = (int*)alloc(NBKT * 4);
    size_t remain = (ws_size > off) ? (ws_size - off) : 0;
    int cap = (int)(remain / 8);
    if (cap > (1 << 20)) cap = (1 << 20);
    int2*  paths   = (int2*)alloc((size_t)cap * 8);

    k_setup<<<NCELL / 256 + 2, 256, 0, stream>>>(pgW, pgB, pm1W, pm1B, pm2W, pm2B, pm3W, pm3B, plW, plB,
                                                 pemb, cell, stats, cursor, rowq, bcnt, cur, dcs, mode,
                                                 gwf, gbf, w1f, b1f, w2f, b2f, w3q, linf, linb);
    k_scatter<<<96, 256, 0, stream>>>((const int*)pei, cell, rowq, row_ptr, dinv, &dcs[0]);
    k_fillmat<<<NCELL / 256 + 96, 256, 0, stream>>>(cell, row_ptr, cursor, col_idx, cntv, pr_row,
                                                    rowq, bcnt, (const int*)px, pemb, mode, gwf, bufA,
                                                    bptr, &dcs[1]);
    k_aggstats<<<96, 256, 0, stream>>>(bufA, row_ptr, col_idx, dinv, gbf, 0, bufB, nrm0, &dcs[2]);
    k_matw1<<<96, 256, 0, stream>>>(bufB, nrm0, gwf, bufA);
    k_aggstats<<<96, 256, 0, stream>>>(bufA, row_ptr, col_idx, dinv, gbf, 1, bufB, nrm1, &dcs[3]);
    k_joinedge<<<96 + 3072 + 96, 256, 0, stream>>>(row_ptr, col_idx, pr_row, rowq, bptr, cur, paths, cap,
                                                   bufB, nrm1, cntv, w1f, b1f, w2f, b2f, xep, mulp, h);
    k_big<<<NBKT, 256, 0, stream>>>(bptr, paths, cell, xep, mulp, w3q, stats, &dcs[4], nrm, cap);
    k_out<<<NPOS / 4, 256, 0, stream>>>((const int*)ppos, row_ptr, col_idx, cell, xep, mulp, h,
                                        w3q, nrm, linf, linb, mode, d_out);
}

// Round 7
// 470.202 us; speedup vs baseline: 1.7051x; 1.7051x over previous
//
#include <hip/hip_runtime.h>
#include <hip/hip_bf16.h>

#define NN 768
#define NE 24576
#define NPOS 4096
#define NCELL (NN*NN)   // 589824 = 2304*256
#define NBLK 2304

typedef __hip_bfloat16 bf16;

__device__ __forceinline__ float ldf(const void* p, int i, int mode) {
    return mode ? __bfloat162float(((const bf16*)p)[i]) : ((const float*)p)[i];
}
__device__ __forceinline__ float aread(float* p) { return atomicAdd(p, 0.f); }

// ---------------- setup: clear cell+pcur+aux, detect dtype, convert weights ----------------
__global__ void k_setup(const void* __restrict__ gW, const void* __restrict__ gB,
                        const void* __restrict__ m1W, const void* __restrict__ m1B,
                        const void* __restrict__ m2W, const void* __restrict__ m2B,
                        const void* __restrict__ m3W, const void* __restrict__ m3B,
                        const void* __restrict__ lW,  const void* __restrict__ lB,
                        const void* __restrict__ emb,
                        int* __restrict__ cell, int* __restrict__ pcur,
                        float* __restrict__ stats, int* __restrict__ cursor,
                        int* __restrict__ rowlen, int* __restrict__ dcs,
                        int* __restrict__ modeg,
                        float* __restrict__ gwf, float* __restrict__ gbf,
                        float* __restrict__ w1f, float* __restrict__ b1f,
                        float* __restrict__ w2f, float* __restrict__ b2f,
                        float* __restrict__ w3q, float* __restrict__ linf, float* __restrict__ linb) {
    int t = threadIdx.x;
    int b = blockIdx.x;
    if (b < NBLK) { cell[b * 256 + t] = 0; return; }
    if (b < 2 * NBLK) { pcur[(b - NBLK) * 256 + t] = 0; return; }
    if (b == 2 * NBLK) {
        for (int i = t; i < NN; i += 256) { cursor[i] = 0; rowlen[i] = 0; }
        if (t < 66) stats[t] = 0.f;
        if (t < 8) dcs[t] = 0;
        return;
    }
    // detect dtype then convert weights
    __shared__ int bad;
    if (t == 0) bad = 0;
    __syncthreads();
    int local = 0;
    for (int i = t; i < 3232; i += 256) {
        float a = fabsf(__bfloat162float(((const bf16*)emb)[i]));
        if (!(a < 100.f)) local = 1;
    }
    if (local) atomicOr(&bad, 1);
    __syncthreads();
    int mode = bad ? 0 : 1;
    if (t == 0) *modeg = mode;
    for (int i = t; i < 2048; i += 256) {
        gwf[i] = ldf(gW, i, mode);
        w1f[i] = ldf(m1W, i, mode);
        w2f[i] = ldf(m2W, i, mode);
    }
    for (int i = t; i < 64; i += 256) { gbf[i] = ldf(gB, i, mode); linf[i] = ldf(lW, i, mode); }
    if (t < 32) { b1f[t] = ldf(m1B, t, mode); b2f[t] = ldf(m2B, t, mode); }
    // w3q row d (stride 36 floats, 16B-aligned): [W3[0..31][d], ind, b3, 0, 0]
    for (int i = t; i < 1056; i += 256) { int c = i >> 5, d = i & 31; w3q[d * 36 + c] = ldf(m3W, i, mode); }
    if (t < 32) { w3q[t * 36 + 33] = ldf(m3B, t, mode); w3q[t * 36 + 34] = 0.f; w3q[t * 36 + 35] = 0.f; }
    if (t == 0) linb[0] = ldf(lB, 0, mode);
}

// ---------------- edge scatter + first-touch rowlen ----------------
__global__ void k_scatter(const int* __restrict__ ei, int* __restrict__ cell, int* __restrict__ rowlen) {
    int e = blockIdx.x * 256 + threadIdx.x;
    int a = ei[e], b = ei[NE + e];
    if ((unsigned)a < (unsigned)NN && (unsigned)b < (unsigned)NN) {
        int old = atomicAdd(&cell[a * NN + b], 1);
        if (old == 0) atomicAdd(&rowlen[a], 1);
    }
}

// ---------------- scan rows (serial thread 0) + dinv ----------------
__global__ void k_scan(const int* __restrict__ rowlen, int* __restrict__ row_ptr, float* __restrict__ dinv) {
    __shared__ int s[NN];
    __shared__ int ps[NN + 1];
    int t = threadIdx.x;
    for (int i = t; i < NN; i += 256) { s[i] = rowlen[i]; dinv[i] = rsqrtf((float)rowlen[i] + 1.0f); }
    __syncthreads();
    if (t == 0) {
        int a = 0;
        for (int i = 0; i < NN; i++) { ps[i] = a; a += s[i]; }
        ps[NN] = a;
    }
    __syncthreads();
    for (int i = t; i <= NN; i += 256) row_ptr[i] = ps[i];
}

// ---------------- parallel CSR fill; cell -> pairIdx in-place ----------------
__global__ void k_fillpar(int* __restrict__ cell, const int* __restrict__ row_ptr, int* __restrict__ cursor,
                          int* __restrict__ col_idx, float* __restrict__ cntv, int* __restrict__ pr_row) {
    int idx = blockIdx.x * 256 + threadIdx.x;
    int i = idx / NN;
    int j = idx - i * NN;
    int cv = cell[idx];
    if (cv > 0) {
        int p = row_ptr[i] + atomicAdd(&cursor[i], 1);
        col_idx[p] = j; cntv[p] = (float)cv; pr_row[p] = i;
        cell[idx] = p;
    } else {
        cell[idx] = -1;
    }
}

// ---------------- path count per cell ----------------
__global__ void k_cnt(const int* __restrict__ row_ptr, const int* __restrict__ col_idx,
                      const int* __restrict__ pr_row, int* __restrict__ pcur) {
    int e1 = blockIdx.x * 256 + threadIdx.x;
    if (e1 >= row_ptr[NN]) return;
    int i = pr_row[e1], k = col_idx[e1];
    int base = i * NN;
    int kb = row_ptr[k], ke = row_ptr[k + 1];
    for (int e2 = kb; e2 < ke; e2++) atomicAdd(&pcur[base + col_idx[e2]], 1);
}

// ---------------- 2-level scan of pcur (589824) ----------------
__global__ void k_scan1(int* __restrict__ pcur, int* __restrict__ bsum) {
    __shared__ int s[256];
    int t = threadIdx.x;
    int n = blockIdx.x * 256 + t;
    int v = pcur[n];
    s[t] = v;
    __syncthreads();
    for (int off = 1; off < 256; off <<= 1) {
        int tmp = (t >= off) ? s[t - off] : 0;
        __syncthreads();
        s[t] += tmp;
        __syncthreads();
    }
    pcur[n] = s[t] - v;   // exclusive within block
    if (t == 255) bsum[blockIdx.x] = s[255];
}

__global__ void k_scan2(const int* __restrict__ bsum, int* __restrict__ boff) {
    __shared__ int s[NBLK];
    int t = threadIdx.x;
    for (int i = t; i < NBLK; i += 256) s[i] = bsum[i];
    __syncthreads();
    if (t == 0) {
        int a = 0;
        for (int i = 0; i < NBLK; i++) { int v = s[i]; s[i] = a; a += v; }
    }
    __syncthreads();
    for (int i = t; i < NBLK; i += 256) boff[i] = s[i];
}

__global__ void k_scan3(int* __restrict__ pcur, const int* __restrict__ boff) {
    int n = blockIdx.x * 256 + threadIdx.x;
    pcur[n] += boff[blockIdx.x];
}

// ---------------- cell-sorted path fill; pcur[n] ends as exclusive END of cell n ----------------
__global__ void k_join2(const int* __restrict__ row_ptr, const int* __restrict__ col_idx,
                        const int* __restrict__ pr_row, int* __restrict__ pcur,
                        int2* __restrict__ paths2, int cap) {
    int e1 = blockIdx.x * 256 + threadIdx.x;
    if (e1 >= row_ptr[NN]) return;
    int i = pr_row[e1], k = col_idx[e1];
    int base = i * NN;
    int kb = row_ptr[k], ke = row_ptr[k + 1];
    for (int e2 = kb; e2 < ke; e2++) {
        int slot = atomicAdd(&pcur[base + col_idx[e2]], 1);
        if (slot < cap) paths2[slot] = make_int2(e1, e2);
    }
}

// ---------------- layer-0: fused emb gather + h @ W0 ----------------
__global__ void k_matw0(const int* __restrict__ x, const void* __restrict__ emb,
                        const int* __restrict__ modep, const float* __restrict__ gwf,
                        float* __restrict__ o) {
    int idx = blockIdx.x * 256 + threadIdx.x;
    int i = idx >> 5, d = idx & 31;
    int mode = *modep;
    int xi = x[i];
    if (xi < 0) xi = 0; if (xi > 100) xi = 100;
    float s = 0.f;
#pragma unroll
    for (int c = 0; c < 32; c++) s += ldf(emb, xi * 32 + c, mode) * gwf[c * 32 + d];
    o[idx] = s;
}

// ---------------- h @ W (layer 1) ----------------
__global__ void k_matw(const float* __restrict__ h, const float* __restrict__ gwf, float* __restrict__ o) {
    int idx = blockIdx.x * 256 + threadIdx.x;
    int i = idx >> 5, d = idx & 31;
    const float* W = gwf + 1024;
    float s = 0.f;
#pragma unroll
    for (int c = 0; c < 32; c++) s += h[i * 32 + c] * W[c * 32 + d];
    o[idx] = s;
}

// ---------------- An @ hw + b ----------------
__global__ void k_agg(const float* __restrict__ hw, const int* __restrict__ row_ptr,
                      const int* __restrict__ col_idx, const float* __restrict__ dinv,
                      const float* __restrict__ gbf, int l, float* __restrict__ o) {
    int idx = blockIdx.x * 256 + threadIdx.x;
    int i = idx >> 5, d = idx & 31;
    int base = row_ptr[i], len = row_ptr[i + 1] - base;
    float di = dinv[i];
    float acc = di * hw[i * 32 + d];
    for (int t = 0; t < len; t++) {
        int c = col_idx[base + t];
        acc += dinv[c] * hw[c * 32 + d];
    }
    o[idx] = di * acc + gbf[l * 32 + d];
}

// ---------------- graph norm + relu (single block) ----------------
__global__ void k_norm(const float* __restrict__ in, float* __restrict__ out) {
    __shared__ float red[1024];
    __shared__ float mean[32], rstd[32];
    int t = threadIdx.x, d = t & 31, g = t >> 5;
    float p = 0.f;
    for (int r = g; r < NN; r += 32) p += in[r * 32 + d];
    red[t] = p;
    __syncthreads();
    if (t < 32) { float s = 0.f; for (int k = 0; k < 32; k++) s += red[k * 32 + t]; mean[t] = s / (float)NN; }
    __syncthreads();
    p = 0.f;
    for (int r = g; r < NN; r += 32) { float v = in[r * 32 + d] - mean[d]; p += v * v; }
    red[t] = p;
    __syncthreads();
    if (t < 32) { float s = 0.f; for (int k = 0; k < 32; k++) s += red[k * 32 + t]; rstd[t] = rsqrtf(s / (float)NN + 1e-5f); }
    __syncthreads();
    for (int e = t; e < NN * 32; e += 1024) {
        int dd = e & 31;
        out[e] = fmaxf((in[e] - mean[dd]) * rstd[dd], 0.f);
    }
}

// ---------------- per-distinct-pair MLP1/MLP2, premultiplied by multiplicity ----------------
__global__ void k_edgemlp(const float* __restrict__ h, const int* __restrict__ row_ptr,
                          const int* __restrict__ col_idx, const int* __restrict__ pr_row,
                          const float* __restrict__ cntv,
                          const float* __restrict__ w1f, const float* __restrict__ b1f,
                          const float* __restrict__ w2f, const float* __restrict__ b2f,
                          float* __restrict__ xep, float* __restrict__ mulp) {
    int t = threadIdx.x, d = t & 31;
    int p = blockIdx.x * 8 + (t >> 5);
    if (p >= NE) return;
    if (p >= row_ptr[NN]) { xep[p * 32 + d] = 0.f; mulp[p * 32 + d] = 0.f; return; }
    int i = pr_row[p], j = col_idx[p];
    float a1 = b1f[d], a2 = b2f[d];
#pragma unroll
    for (int c = 0; c < 32; c++) {
        float hv = h[i * 32 + c];
        a1 += hv * w1f[c * 32 + d];
        a2 += hv * w2f[c * 32 + d];
    }
#pragma unroll
    for (int c = 0; c < 32; c++) {
        float hv = h[j * 32 + c];
        a1 += hv * w1f[(32 + c) * 32 + d];
        a2 += hv * w2f[(32 + c) * 32 + d];
    }
    float cv = cntv[p];
    xep[p * 32 + d]  = cv * fmaxf(a1, 0.f);
    mulp[p * 32 + d] = cv * fmaxf(a2, 0.f);
}

#define DOT4(Z, A, W) Z += A.x * W.x + A.y * W.y + A.z * W.z + A.w * W.w

// ---------------- fused: exact per-cell path gather + z + masked stats ----------------
__global__ __launch_bounds__(256) void k_big(const int* __restrict__ pcur, const int2* __restrict__ paths2,
                                             const int* __restrict__ cell,
                                             const float4* __restrict__ xep4, const float4* __restrict__ mulp4,
                                             const float* __restrict__ w3q,
                                             float* __restrict__ stats, int* __restrict__ done,
                                             float* __restrict__ nrm, int cap) {
    __shared__ float ws1[4][32], ws2[4][32], wcm[4];
    __shared__ int amlast;
    int t = threadIdx.x, lane = t & 63, w = t >> 6;
    int n = blockIdx.x * 256 + t;       // one cell per thread
    int p1 = pcur[n];
    int p0 = (n == 0) ? 0 : pcur[n - 1];
    if (p0 > cap) p0 = cap; if (p1 > cap) p1 = cap;
    float4 a0 = {0.f,0.f,0.f,0.f}, a1 = a0, a2 = a0, a3 = a0, a4 = a0, a5 = a0, a6 = a0, a7 = a0;
    for (int p = p0; p < p1; p++) {
        int2 rec = paths2[p];
        const float4* xr = xep4 + rec.x * 8;
        const float4* mr = mulp4 + rec.y * 8;
        float4 x, m;
        x = xr[0]; m = mr[0]; a0.x += x.x*m.x; a0.y += x.y*m.y; a0.z += x.z*m.z; a0.w += x.w*m.w;
        x = xr[1]; m = mr[1]; a1.x += x.x*m.x; a1.y += x.y*m.y; a1.z += x.z*m.z; a1.w += x.w*m.w;
        x = xr[2]; m = mr[2]; a2.x += x.x*m.x; a2.y += x.y*m.y; a2.z += x.z*m.z; a2.w += x.w*m.w;
        x = xr[3]; m = mr[3]; a3.x += x.x*m.x; a3.y += x.y*m.y; a3.z += x.z*m.z; a3.w += x.w*m.w;
        x = xr[4]; m = mr[4]; a4.x += x.x*m.x; a4.y += x.y*m.y; a4.z += x.z*m.z; a4.w += x.w*m.w;
        x = xr[5]; m = mr[5]; a5.x += x.x*m.x; a5.y += x.y*m.y; a5.z += x.z*m.z; a5.w += x.w*m.w;
        x = xr[6]; m = mr[6]; a6.x += x.x*m.x; a6.y += x.y*m.y; a6.z += x.z*m.z; a6.w += x.w*m.w;
        x = xr[7]; m = mr[7]; a7.x += x.x*m.x; a7.y += x.y*m.y; a7.z += x.z*m.z; a7.w += x.w*m.w;
    }
    bool adj = cell[n] >= 0;
    float af = adj ? 1.f : 0.f;
    float msk = (p1 > p0 || adj) ? 1.f : 0.f;
    float s1[32], s2[32];
#pragma unroll
    for (int dd = 0; dd < 32; dd++) {
        const float4* wr = (const float4*)(w3q + dd * 36);   // wave-uniform -> scalar s_load
        float4 wv = wr[8];                                   // x = ind weight, y = b3
        float z = wv.y + af * wv.x;
        wv = wr[0]; DOT4(z, a0, wv);
        wv = wr[1]; DOT4(z, a1, wv);
        wv = wr[2]; DOT4(z, a2, wv);
        wv = wr[3]; DOT4(z, a3, wv);
        wv = wr[4]; DOT4(z, a4, wv);
        wv = wr[5]; DOT4(z, a5, wv);
        wv = wr[6]; DOT4(z, a6, wv);
        wv = wr[7]; DOT4(z, a7, wv);
        s1[dd] = msk * z;
        s2[dd] = msk * z * z;
    }
    float cm = msk;
    // wave butterflies, cross-wave LDS, global atomics (R4-proven tail)
#pragma unroll
    for (int d = 0; d < 32; d++) {
        float v = s1[d];
        for (int off = 32; off >= 1; off >>= 1) v += __shfl_xor(v, off);
        if (lane == 0) ws1[w][d] = v;
        float u = s2[d];
        for (int off = 32; off >= 1; off >>= 1) u += __shfl_xor(u, off);
        if (lane == 0) ws2[w][d] = u;
    }
    {
        float v = cm;
        for (int off = 32; off >= 1; off >>= 1) v += __shfl_xor(v, off);
        if (lane == 0) wcm[w] = v;
    }
    __syncthreads();
    if (t < 32) {
        float a = 0.f, b = 0.f;
        for (int k = 0; k < 4; k++) { a += ws1[k][t]; b += ws2[k][t]; }
        atomicAdd(&stats[t], a);
        atomicAdd(&stats[32 + t], b);
    }
    if (t == 64) atomicAdd(&stats[64], wcm[0] + wcm[1] + wcm[2] + wcm[3]);
    __syncthreads();
    if (t == 0) {
        __threadfence();
        amlast = (atomicAdd(done, 1) == NBLK - 1) ? 1 : 0;
    }
    __syncthreads();
    if (amlast && t < 32) {
        float sum1 = aread(&stats[t]);
        float sum2 = aread(&stats[32 + t]);
        float cmv  = aread(&stats[64]);
        if (cmv < 1.f) cmv = 1.f;
        float mean = sum1 / cmv;
        float var = sum2 / cmv - mean * mean;
        nrm[t] = mean;
        nrm[32 + t] = rsqrtf(fmaxf(var, 0.f) + 1e-5f);
    }
}

// ---------------- output: recompute C at pos pairs, norm, sym, linear ----------------
__global__ void k_out(const int* __restrict__ pos, const int* __restrict__ row_ptr,
                      const int* __restrict__ col_idx, const int* __restrict__ cell,
                      const float* __restrict__ xep, const float* __restrict__ mulp,
                      const float* __restrict__ h,
                      const float* __restrict__ w3q,
                      const float* __restrict__ nrm,
                      const float* __restrict__ linf, const float* __restrict__ linb,
                      const int* __restrict__ modep, void* __restrict__ outp) {
    __shared__ float Cb[4][2][32];
    int t = threadIdx.x;
    int w = t >> 6, lane = t & 63, d = lane & 31, dir = lane >> 5;
    int p = blockIdx.x * 4 + w;
    int a = pos[2 * p], b = pos[2 * p + 1];
    if ((unsigned)a >= (unsigned)NN) a = 0;
    if ((unsigned)b >= (unsigned)NN) b = 0;
    int r = dir ? b : a;
    int cc = dir ? a : b;
    int base = row_ptr[r], len = row_ptr[r + 1] - base;
    float acc = 0.f;
    bool hit = false;
    for (int tt = 0; tt < len; tt++) {
        int e1 = base + tt;
        int k = col_idx[e1];
        int e2 = cell[k * NN + cc];
        if (e2 >= 0) { hit = true; acc += xep[e1 * 32 + d] * mulp[e2 * 32 + d]; }
    }
    Cb[w][dir][d] = acc;
    bool adj = cell[r * NN + cc] >= 0;
    float msk = (hit || adj) ? 1.f : 0.f;
    __syncthreads();
    float z = w3q[d * 36 + 33] + (adj ? 1.f : 0.f) * w3q[d * 36 + 32];
#pragma unroll
    for (int c = 0; c < 32; c++) z += Cb[w][dir][c] * w3q[d * 36 + c];
    float zn = fmaxf((z - nrm[d]) * nrm[32 + d], 0.f);
    float zp = __shfl_xor(zn, 32);
    float symd = msk * zn * zp;
    float xxd = h[a * 32 + d] * h[b * 32 + d];
    float contrib = symd * linf[d] + xxd * linf[32 + d];
    for (int off = 16; off >= 1; off >>= 1) contrib += __shfl_xor(contrib, off);
    if (lane == 0) {
        float v = contrib + linb[0];
        v = fminf(fmaxf(v, -1e4f), 1e4f);
        if (*modep) ((bf16*)outp)[p] = __float2bfloat16(v);
        else        ((float*)outp)[p] = v;
    }
}

extern "C" void kernel_launch(void* const* d_in, const int* in_sizes, int n_in,
                              void* d_out, int out_size, void* d_ws, size_t ws_size,
                              hipStream_t stream) {
    const void* px  = d_in[0];  const void* pei = d_in[1];  const void* ppos = d_in[2];
    const void* pemb = d_in[3]; const void* pgW = d_in[4];  const void* pgB  = d_in[5];
    const void* pm1W = d_in[6]; const void* pm1B = d_in[7]; const void* pm2W = d_in[8];
    const void* pm2B = d_in[9]; const void* pm3W = d_in[10]; const void* pm3B = d_in[11];
    const void* plW = d_in[12]; const void* plB = d_in[13];
    {
        int c2048 = 0, c64 = 0, c32 = 0;
        for (int i = 0; i < n_in; i++) {
            int s = in_sizes[i]; const void* p = d_in[i];
            switch (s) {
                case 768:   px = p; break;
                case 49152: pei = p; break;
                case 8192:  ppos = p; break;
                case 3232:  pemb = p; break;
                case 2048:  if (c2048 == 0) pgW = p; else if (c2048 == 1) pm1W = p; else pm2W = p; c2048++; break;
                case 64:    if (c64 == 0) pgB = p; else plW = p; c64++; break;
                case 32:    if (c32 == 0) pm1B = p; else if (c32 == 1) pm2B = p; else pm3B = p; c32++; break;
                case 1056:  pm3W = p; break;
                case 1:     plB = p; break;
                default: break;
            }
        }
    }

    char* ws = (char*)d_ws;
    size_t off = 0;
    auto alloc = [&](size_t bytes) -> void* {
        void* pp = ws + off;
        off += (bytes + 255) & ~(size_t)255;
        return pp;
    };
    int*   cell    = (int*)alloc(NCELL * 4);       // counts -> pairIdx in-place
    int*   pcur    = (int*)alloc(NCELL * 4);       // path counts -> scan -> CSR ends
    int*   rowlen  = (int*)alloc(NN * 4);
    int*   row_ptr = (int*)alloc((NN + 1) * 4);
    int*   col_idx = (int*)alloc(NE * 4);
    float* cntv    = (float*)alloc(NE * 4);
    int*   pr_row  = (int*)alloc(NE * 4);
    int*   cursor  = (int*)alloc(NN * 4);
    float* dinv    = (float*)alloc(NN * 4);
    float* h       = (float*)alloc(NN * 32 * 4);
    float* bufA    = (float*)alloc(NN * 32 * 4);
    float* bufB    = (float*)alloc(NN * 32 * 4);
    float* xep     = (float*)alloc(NE * 32 * 4);
    float* mulp    = (float*)alloc(NE * 32 * 4);
    float* stats   = (float*)alloc(66 * 4);
    float* nrm     = (float*)alloc(64 * 4);
    float* gwf     = (float*)alloc(2048 * 4);
    float* gbf     = (float*)alloc(64 * 4);
    float* w1f     = (float*)alloc(2048 * 4);
    float* b1f     = (float*)alloc(32 * 4);
    float* w2f     = (float*)alloc(2048 * 4);
    float* b2f     = (float*)alloc(32 * 4);
    float* w3q     = (float*)alloc(32 * 36 * 4);
    float* linf    = (float*)alloc(64 * 4);
    float* linb    = (float*)alloc(4);
    int*   mode    = (int*)alloc(4);
    int*   dcs     = (int*)alloc(8 * 4);
    int*   bsum    = (int*)alloc(NBLK * 4);
    int*   boff    = (int*)alloc(NBLK * 4);
    size_t remain = (ws_size > off) ? (ws_size - off) : 0;
    int cap = (int)(remain / 8);
    if (cap > (1 << 20)) cap = (1 << 20);
    int2*  paths2  = (int2*)alloc((size_t)cap * 8);

    k_setup<<<2 * NBLK + 2, 256, 0, stream>>>(pgW, pgB, pm1W, pm1B, pm2W, pm2B, pm3W, pm3B, plW, plB,
                                              pemb, cell, pcur, stats, cursor, rowlen, dcs, mode,
                                              gwf, gbf, w1f, b1f, w2f, b2f, w3q, linf, linb);
    k_scatter<<<96, 256, 0, stream>>>((const int*)pei, cell, rowlen);
    k_scan<<<1, 256, 0, stream>>>(rowlen, row_ptr, dinv);
    k_fillpar<<<NBLK, 256, 0, stream>>>(cell, row_ptr, cursor, col_idx, cntv, pr_row);
    // path machinery (independent of GCN chain)
    k_cnt<<<96, 256, 0, stream>>>(row_ptr, col_idx, pr_row, pcur);
    k_scan1<<<NBLK, 256, 0, stream>>>(pcur, bsum);
    k_scan2<<<1, 256, 0, stream>>>(bsum, boff);
    k_scan3<<<NBLK, 256, 0, stream>>>(pcur, boff);
    k_join2<<<96, 256, 0, stream>>>(row_ptr, col_idx, pr_row, pcur, paths2, cap);
    // GCN chain
    k_matw0<<<96, 256, 0, stream>>>((const int*)px, pemb, mode, gwf, bufA);
    k_agg<<<96, 256, 0, stream>>>(bufA, row_ptr, col_idx, dinv, gbf, 0, bufB);
    k_norm<<<1, 1024, 0, stream>>>(bufB, h);
    k_matw<<<96, 256, 0, stream>>>(h, gwf, bufA);
    k_agg<<<96, 256, 0, stream>>>(bufA, row_ptr, col_idx, dinv, gbf, 1, bufB);
    k_norm<<<1, 1024, 0, stream>>>(bufB, h);
    k_edgemlp<<<NE / 8, 256, 0, stream>>>(h, row_ptr, col_idx, pr_row, cntv, w1f, b1f, w2f, b2f, xep, mulp);
    // fused big pass + output
    k_big<<<NBLK, 256, 0, stream>>>(pcur, paths2, cell, (const float4*)xep, (const float4*)mulp,
                                    w3q, stats, &dcs[0], nrm, cap);
    k_out<<<NPOS / 4, 256, 0, stream>>>((const int*)ppos, row_ptr, col_idx, cell, xep, mulp, h,
                                        w3q, nrm, linf, linb, mode, d_out);
}

// Round 8
// 406.036 us; speedup vs baseline: 1.9745x; 1.1580x over previous
//
#include <hip/hip_runtime.h>
#include <hip/hip_bf16.h>

#define NN 768
#define NE 24576
#define NPOS 4096
#define NCELL (NN*NN)   // 589824 = 2304*256
#define NBLK 2304

typedef __hip_bfloat16 bf16;

__device__ __forceinline__ float ldf(const void* p, int i, int mode) {
    return mode ? __bfloat162float(((const bf16*)p)[i]) : ((const float*)p)[i];
}
__device__ __forceinline__ float aread(float* p) { return atomicAdd(p, 0.f); }

// value-splitting pairwise reduction round: after this, lanes with bit D clear
// own v[0..HALF) = summed lower half, lanes with bit D set own upper half.
template<int D, int HALF>
__device__ __forceinline__ void redRound(float* v, int lane) {
#pragma unroll
    for (int i = 0; i < HALF; i++) {
        float snd = (lane & D) ? v[i] : v[i + HALF];
        float r = __shfl_xor(snd, D);
        v[i] = ((lane & D) ? v[i + HALF] : v[i]) + r;
    }
}

// ---------------- setup: clear cell+pcur+aux, detect dtype, convert weights ----------------
__global__ void k_setup(const void* __restrict__ gW, const void* __restrict__ gB,
                        const void* __restrict__ m1W, const void* __restrict__ m1B,
                        const void* __restrict__ m2W, const void* __restrict__ m2B,
                        const void* __restrict__ m3W, const void* __restrict__ m3B,
                        const void* __restrict__ lW,  const void* __restrict__ lB,
                        const void* __restrict__ emb,
                        int* __restrict__ cell, int* __restrict__ pcur,
                        float* __restrict__ stats, int* __restrict__ cursor,
                        int* __restrict__ rowlen, int* __restrict__ dcs,
                        int* __restrict__ modeg,
                        float* __restrict__ gwf, float* __restrict__ gbf,
                        float* __restrict__ w1f, float* __restrict__ b1f,
                        float* __restrict__ w2f, float* __restrict__ b2f,
                        float* __restrict__ w3q, float* __restrict__ linf, float* __restrict__ linb) {
    int t = threadIdx.x;
    int b = blockIdx.x;
    if (b < NBLK) { cell[b * 256 + t] = 0; return; }
    if (b < 2 * NBLK) { pcur[(b - NBLK) * 256 + t] = 0; return; }
    if (b == 2 * NBLK) {
        for (int i = t; i < NN; i += 256) { cursor[i] = 0; rowlen[i] = 0; }
        if (t < 66) stats[t] = 0.f;
        if (t < 8) dcs[t] = 0;
        return;
    }
    __shared__ int bad;
    if (t == 0) bad = 0;
    __syncthreads();
    int local = 0;
    for (int i = t; i < 3232; i += 256) {
        float a = fabsf(__bfloat162float(((const bf16*)emb)[i]));
        if (!(a < 100.f)) local = 1;
    }
    if (local) atomicOr(&bad, 1);
    __syncthreads();
    int mode = bad ? 0 : 1;
    if (t == 0) *modeg = mode;
    for (int i = t; i < 2048; i += 256) {
        gwf[i] = ldf(gW, i, mode);
        w1f[i] = ldf(m1W, i, mode);
        w2f[i] = ldf(m2W, i, mode);
    }
    for (int i = t; i < 64; i += 256) { gbf[i] = ldf(gB, i, mode); linf[i] = ldf(lW, i, mode); }
    if (t < 32) { b1f[t] = ldf(m1B, t, mode); b2f[t] = ldf(m2B, t, mode); }
    // w3q row d (stride 36 floats, 16B-aligned): [W3[0..31][d], ind, b3, 0, 0]
    for (int i = t; i < 1056; i += 256) { int c = i >> 5, d = i & 31; w3q[d * 36 + c] = ldf(m3W, i, mode); }
    if (t < 32) { w3q[t * 36 + 33] = ldf(m3B, t, mode); w3q[t * 36 + 34] = 0.f; w3q[t * 36 + 35] = 0.f; }
    if (t == 0) linb[0] = ldf(lB, 0, mode);
}

// ---------------- edge scatter + first-touch rowlen ----------------
__global__ void k_scatter(const int* __restrict__ ei, int* __restrict__ cell, int* __restrict__ rowlen) {
    int e = blockIdx.x * 256 + threadIdx.x;
    int a = ei[e], b = ei[NE + e];
    if ((unsigned)a < (unsigned)NN && (unsigned)b < (unsigned)NN) {
        int old = atomicAdd(&cell[a * NN + b], 1);
        if (old == 0) atomicAdd(&rowlen[a], 1);
    }
}

// ---------------- parallel scan of rowlen (768 threads, Hillis-Steele) + dinv ----------------
__global__ void k_scan(const int* __restrict__ rowlen, int* __restrict__ row_ptr, float* __restrict__ dinv) {
    __shared__ int s[NN];
    int t = threadIdx.x;   // 768 threads
    int v = rowlen[t];
    s[t] = v;
    dinv[t] = rsqrtf((float)v + 1.0f);
    __syncthreads();
    for (int off = 1; off < NN; off <<= 1) {
        int tmp = (t >= off) ? s[t - off] : 0;
        __syncthreads();
        s[t] += tmp;
        __syncthreads();
    }
    row_ptr[t] = s[t] - v;
    if (t == NN - 1) row_ptr[NN] = s[t];
}

// ---------------- parallel CSR fill; cell -> pairIdx in-place ----------------
__global__ void k_fillpar(int* __restrict__ cell, const int* __restrict__ row_ptr, int* __restrict__ cursor,
                          int* __restrict__ col_idx, float* __restrict__ cntv, int* __restrict__ pr_row) {
    int idx = blockIdx.x * 256 + threadIdx.x;
    int i = idx / NN;
    int j = idx - i * NN;
    int cv = cell[idx];
    if (cv > 0) {
        int p = row_ptr[i] + atomicAdd(&cursor[i], 1);
        col_idx[p] = j; cntv[p] = (float)cv; pr_row[p] = i;
        cell[idx] = p;
    } else {
        cell[idx] = -1;
    }
}

// ---------------- path count per cell: one WAVE per e1 edge ----------------
__global__ void k_cnt(const int* __restrict__ row_ptr, const int* __restrict__ col_idx,
                      const int* __restrict__ pr_row, int* __restrict__ pcur) {
    int wid = (blockIdx.x * 256 + threadIdx.x) >> 6;
    int lane = threadIdx.x & 63;
    if (wid >= row_ptr[NN]) return;
    int i = pr_row[wid], k = col_idx[wid];
    int base = i * NN;
    int kb = row_ptr[k], ke = row_ptr[k + 1];
    for (int e = kb + lane; e < ke; e += 64) atomicAdd(&pcur[base + col_idx[e]], 1);
}

// ---------------- block-local scan of pcur; bsum = per-block totals ----------------
__global__ void k_scan1(int* __restrict__ pcur, int* __restrict__ bsum) {
    __shared__ int s[256];
    int t = threadIdx.x;
    int n = blockIdx.x * 256 + t;
    int v = pcur[n];
    s[t] = v;
    __syncthreads();
    for (int off = 1; off < 256; off <<= 1) {
        int tmp = (t >= off) ? s[t - off] : 0;
        __syncthreads();
        s[t] += tmp;
        __syncthreads();
    }
    pcur[n] = s[t] - v;   // exclusive within block
    if (t == 255) bsum[blockIdx.x] = s[255];
}

// ---------------- scan block sums (768 threads x 3) -> boff ----------------
__global__ void k_scan2(const int* __restrict__ bsum, int* __restrict__ boff) {
    __shared__ int s[768];
    int t = threadIdx.x;   // 768 threads
    int b0 = bsum[3 * t], b1 = bsum[3 * t + 1], b2 = bsum[3 * t + 2];
    int v = b0 + b1 + b2;
    s[t] = v;
    __syncthreads();
    for (int off = 1; off < 768; off <<= 1) {
        int tmp = (t >= off) ? s[t - off] : 0;
        __syncthreads();
        s[t] += tmp;
        __syncthreads();
    }
    int base = s[t] - v;
    boff[3 * t] = base;
    boff[3 * t + 1] = base + b0;
    boff[3 * t + 2] = base + b0 + b1;
}

// ---------------- cell-sorted path fill (wave per e1); pcur[n] -> local excl END ----------------
__global__ void k_join2(const int* __restrict__ row_ptr, const int* __restrict__ col_idx,
                        const int* __restrict__ pr_row, int* __restrict__ pcur,
                        const int* __restrict__ boff,
                        int2* __restrict__ paths2, int cap) {
    int wid = (blockIdx.x * 256 + threadIdx.x) >> 6;
    int lane = threadIdx.x & 63;
    if (wid >= row_ptr[NN]) return;
    int i = pr_row[wid], k = col_idx[wid];
    int base = i * NN;
    int kb = row_ptr[k], ke = row_ptr[k + 1];
    for (int e = kb + lane; e < ke; e += 64) {
        int celln = base + col_idx[e];
        int slot = boff[celln >> 8] + atomicAdd(&pcur[celln], 1);
        if (slot < cap) paths2[slot] = make_int2(wid, e);
    }
}

// ---------------- layer-0: fused emb gather + h @ W0 ----------------
__global__ void k_matw0(const int* __restrict__ x, const void* __restrict__ emb,
                        const int* __restrict__ modep, const float* __restrict__ gwf,
                        float* __restrict__ o) {
    int idx = blockIdx.x * 256 + threadIdx.x;
    int i = idx >> 5, d = idx & 31;
    int mode = *modep;
    int xi = x[i];
    if (xi < 0) xi = 0; if (xi > 100) xi = 100;
    float s = 0.f;
#pragma unroll
    for (int c = 0; c < 32; c++) s += ldf(emb, xi * 32 + c, mode) * gwf[c * 32 + d];
    o[idx] = s;
}

// ---------------- h @ W (layer 1) ----------------
__global__ void k_matw(const float* __restrict__ h, const float* __restrict__ gwf, float* __restrict__ o) {
    int idx = blockIdx.x * 256 + threadIdx.x;
    int i = idx >> 5, d = idx & 31;
    const float* W = gwf + 1024;
    float s = 0.f;
#pragma unroll
    for (int c = 0; c < 32; c++) s += h[i * 32 + c] * W[c * 32 + d];
    o[idx] = s;
}

// ---------------- An @ hw + b ----------------
__global__ void k_agg(const float* __restrict__ hw, const int* __restrict__ row_ptr,
                      const int* __restrict__ col_idx, const float* __restrict__ dinv,
                      const float* __restrict__ gbf, int l, float* __restrict__ o) {
    int idx = blockIdx.x * 256 + threadIdx.x;
    int i = idx >> 5, d = idx & 31;
    int base = row_ptr[i], len = row_ptr[i + 1] - base;
    float di = dinv[i];
    float acc = di * hw[i * 32 + d];
    for (int t = 0; t < len; t++) {
        int c = col_idx[base + t];
        acc += dinv[c] * hw[c * 32 + d];
    }
    o[idx] = di * acc + gbf[l * 32 + d];
}

// ---------------- graph norm + relu (single block) ----------------
__global__ void k_norm(const float* __restrict__ in, float* __restrict__ out) {
    __shared__ float red[1024];
    __shared__ float mean[32], rstd[32];
    int t = threadIdx.x, d = t & 31, g = t >> 5;
    float p = 0.f;
    for (int r = g; r < NN; r += 32) p += in[r * 32 + d];
    red[t] = p;
    __syncthreads();
    if (t < 32) { float s = 0.f; for (int k = 0; k < 32; k++) s += red[k * 32 + t]; mean[t] = s / (float)NN; }
    __syncthreads();
    p = 0.f;
    for (int r = g; r < NN; r += 32) { float v = in[r * 32 + d] - mean[d]; p += v * v; }
    red[t] = p;
    __syncthreads();
    if (t < 32) { float s = 0.f; for (int k = 0; k < 32; k++) s += red[k * 32 + t]; rstd[t] = rsqrtf(s / (float)NN + 1e-5f); }
    __syncthreads();
    for (int e = t; e < NN * 32; e += 1024) {
        int dd = e & 31;
        out[e] = fmaxf((in[e] - mean[dd]) * rstd[dd], 0.f);
    }
}

// ---------------- per-distinct-pair MLP1/MLP2, premultiplied by multiplicity ----------------
__global__ void k_edgemlp(const float* __restrict__ h, const int* __restrict__ row_ptr,
                          const int* __restrict__ col_idx, const int* __restrict__ pr_row,
                          const float* __restrict__ cntv,
                          const float* __restrict__ w1f, const float* __restrict__ b1f,
                          const float* __restrict__ w2f, const float* __restrict__ b2f,
                          float* __restrict__ xep, float* __restrict__ mulp) {
    int t = threadIdx.x, d = t & 31;
    int p = blockIdx.x * 8 + (t >> 5);
    if (p >= NE) return;
    if (p >= row_ptr[NN]) { xep[p * 32 + d] = 0.f; mulp[p * 32 + d] = 0.f; return; }
    int i = pr_row[p], j = col_idx[p];
    float a1 = b1f[d], a2 = b2f[d];
#pragma unroll
    for (int c = 0; c < 32; c++) {
        float hv = h[i * 32 + c];
        a1 += hv * w1f[c * 32 + d];
        a2 += hv * w2f[c * 32 + d];
    }
#pragma unroll
    for (int c = 0; c < 32; c++) {
        float hv = h[j * 32 + c];
        a1 += hv * w1f[(32 + c) * 32 + d];
        a2 += hv * w2f[(32 + c) * 32 + d];
    }
    float cv = cntv[p];
    xep[p * 32 + d]  = cv * fmaxf(a1, 0.f);
    mulp[p * 32 + d] = cv * fmaxf(a2, 0.f);
}

#define DOT4(Z, A, W) Z += A.x * W.x + A.y * W.y + A.z * W.z + A.w * W.w

// ---------------- fused: exact per-cell path gather + z + masked stats ----------------
__global__ __launch_bounds__(256, 4) void k_big(const int* __restrict__ pcur, const int* __restrict__ boff,
                                                const int2* __restrict__ paths2,
                                                const int* __restrict__ cell,
                                                const float4* __restrict__ xep4, const float4* __restrict__ mulp4,
                                                const float* __restrict__ w3q,
                                                float* __restrict__ stats, int* __restrict__ done,
                                                float* __restrict__ nrm, int cap) {
    __shared__ float sS1[32], sS2[32];
    __shared__ float sCm;
    __shared__ int amlast;
    int t = threadIdx.x, lane = t & 63;
    int b = blockIdx.x;
    int n = b * 256 + t;        // one cell per thread
    if (t == 0) sCm = 0.f;
    if (t < 32) { sS1[t] = 0.f; sS2[t] = 0.f; }
    __syncthreads();
    int bo = boff[b];
    int p1 = bo + pcur[n];
    int p0 = (t == 0) ? bo : bo + pcur[n - 1];
    if (p0 > cap) p0 = cap; if (p1 > cap) p1 = cap;
    float4 a0 = {0.f,0.f,0.f,0.f}, a1 = a0, a2 = a0, a3 = a0, a4 = a0, a5 = a0, a6 = a0, a7 = a0;
    for (int p = p0; p < p1; p++) {
        int2 rec = paths2[p];
        const float4* xr = xep4 + rec.x * 8;
        const float4* mr = mulp4 + rec.y * 8;
        float4 x, m;
        x = xr[0]; m = mr[0]; a0.x += x.x*m.x; a0.y += x.y*m.y; a0.z += x.z*m.z; a0.w += x.w*m.w;
        x = xr[1]; m = mr[1]; a1.x += x.x*m.x; a1.y += x.y*m.y; a1.z += x.z*m.z; a1.w += x.w*m.w;
        x = xr[2]; m = mr[2]; a2.x += x.x*m.x; a2.y += x.y*m.y; a2.z += x.z*m.z; a2.w += x.w*m.w;
        x = xr[3]; m = mr[3]; a3.x += x.x*m.x; a3.y += x.y*m.y; a3.z += x.z*m.z; a3.w += x.w*m.w;
        x = xr[4]; m = mr[4]; a4.x += x.x*m.x; a4.y += x.y*m.y; a4.z += x.z*m.z; a4.w += x.w*m.w;
        x = xr[5]; m = mr[5]; a5.x += x.x*m.x; a5.y += x.y*m.y; a5.z += x.z*m.z; a5.w += x.w*m.w;
        x = xr[6]; m = mr[6]; a6.x += x.x*m.x; a6.y += x.y*m.y; a6.z += x.z*m.z; a6.w += x.w*m.w;
        x = xr[7]; m = mr[7]; a7.x += x.x*m.x; a7.y += x.y*m.y; a7.z += x.z*m.z; a7.w += x.w*m.w;
    }
    bool adj = cell[n] >= 0;
    float af = adj ? 1.f : 0.f;
    float msk = (p1 > p0 || adj) ? 1.f : 0.f;
    // z epilogue + reduction in two chunks of 16 dims (keeps VGPR pressure low)
#pragma unroll
    for (int ch = 0; ch < 2; ch++) {
        float v[32];
#pragma unroll
        for (int j = 0; j < 16; j++) {
            int dd = ch * 16 + j;
            const float4* wr = (const float4*)(w3q + dd * 36);   // wave-uniform -> scalar s_load
            float4 wv = wr[8];                                   // x = ind weight, y = b3
            float z = wv.y + af * wv.x;
            wv = wr[0]; DOT4(z, a0, wv);
            wv = wr[1]; DOT4(z, a1, wv);
            wv = wr[2]; DOT4(z, a2, wv);
            wv = wr[3]; DOT4(z, a3, wv);
            wv = wr[4]; DOT4(z, a4, wv);
            wv = wr[5]; DOT4(z, a5, wv);
            wv = wr[6]; DOT4(z, a6, wv);
            wv = wr[7]; DOT4(z, a7, wv);
            v[j] = msk * z;
            v[16 + j] = msk * z * z;
        }
        // pairwise over XOR 32 (duplicates halves), then split rounds over bits 16..1
#pragma unroll
        for (int i2 = 0; i2 < 32; i2++) v[i2] += __shfl_xor(v[i2], 32);
        redRound<16, 16>(v, lane);
        redRound<8, 8>(v, lane);
        redRound<4, 4>(v, lane);
        redRound<2, 2>(v, lane);
        redRound<1, 1>(v, lane);
        // lane l (<32) now owns block-wave sum for value index l (0..15: z, 16..31: z^2)
        if (lane < 32) {
            if (lane < 16) atomicAdd(&sS1[ch * 16 + lane], v[0]);
            else           atomicAdd(&sS2[ch * 16 + lane - 16], v[0]);
        }
    }
    {
        float cm = msk;
        for (int off = 32; off >= 1; off >>= 1) cm += __shfl_xor(cm, off);
        if (lane == 0) atomicAdd(&sCm, cm);
    }
    __syncthreads();
    if (t < 32) {
        atomicAdd(&stats[t], sS1[t]);
        atomicAdd(&stats[32 + t], sS2[t]);
    }
    if (t == 32) atomicAdd(&stats[64], sCm);
    __syncthreads();
    if (t == 0) {
        __threadfence();
        amlast = (atomicAdd(done, 1) == NBLK - 1) ? 1 : 0;
    }
    __syncthreads();
    if (amlast && t < 32) {
        float sum1 = aread(&stats[t]);
        float sum2 = aread(&stats[32 + t]);
        float cmv  = aread(&stats[64]);
        if (cmv < 1.f) cmv = 1.f;
        float mean = sum1 / cmv;
        float var = sum2 / cmv - mean * mean;
        nrm[t] = mean;
        nrm[32 + t] = rsqrtf(fmaxf(var, 0.f) + 1e-5f);
    }
}

// ---------------- output: C at pos pairs via path lists, norm, sym, linear ----------------
__global__ void k_out(const int* __restrict__ pos, const int* __restrict__ pcur,
                      const int* __restrict__ boff, const int2* __restrict__ paths2,
                      const int* __restrict__ cell,
                      const float* __restrict__ xep, const float* __restrict__ mulp,
                      const float* __restrict__ h,
                      const float* __restrict__ w3q,
                      const float* __restrict__ nrm,
                      const float* __restrict__ linf, const float* __restrict__ linb,
                      const int* __restrict__ modep, int cap, void* __restrict__ outp) {
    __shared__ float Cb[4][2][32];
    int t = threadIdx.x;
    int w = t >> 6, lane = t & 63, d = lane & 31, dir = lane >> 5;
    int p = blockIdx.x * 4 + w;
    int a = pos[2 * p], b = pos[2 * p + 1];
    if ((unsigned)a >= (unsigned)NN) a = 0;
    if ((unsigned)b >= (unsigned)NN) b = 0;
    int r = dir ? b : a;
    int cc = dir ? a : b;
    int n = r * NN + cc;
    int nb = n >> 8;
    int p1 = boff[nb] + pcur[n];
    int p0 = ((n & 255) == 0) ? boff[nb] : boff[nb] + pcur[n - 1];
    if (p0 > cap) p0 = cap; if (p1 > cap) p1 = cap;
    float acc = 0.f;
    for (int q = p0; q < p1; q++) {
        int2 rec = paths2[q];
        acc += xep[rec.x * 32 + d] * mulp[rec.y * 32 + d];
    }
    Cb[w][dir][d] = acc;
    bool adj = cell[n] >= 0;
    float msk = (p1 > p0 || adj) ? 1.f : 0.f;
    __syncthreads();
    float z = w3q[d * 36 + 33] + (adj ? 1.f : 0.f) * w3q[d * 36 + 32];
#pragma unroll
    for (int c = 0; c < 32; c++) z += Cb[w][dir][c] * w3q[d * 36 + c];
    float zn = fmaxf((z - nrm[d]) * nrm[32 + d], 0.f);
    float zp = __shfl_xor(zn, 32);
    float symd = msk * zn * zp;
    float xxd = h[a * 32 + d] * h[b * 32 + d];
    float contrib = symd * linf[d] + xxd * linf[32 + d];
    for (int off = 16; off >= 1; off >>= 1) contrib += __shfl_xor(contrib, off);
    if (lane == 0) {
        float v = contrib + linb[0];
        v = fminf(fmaxf(v, -1e4f), 1e4f);
        if (*modep) ((bf16*)outp)[p] = __float2bfloat16(v);
        else        ((float*)outp)[p] = v;
    }
}

extern "C" void kernel_launch(void* const* d_in, const int* in_sizes, int n_in,
                              void* d_out, int out_size, void* d_ws, size_t ws_size,
                              hipStream_t stream) {
    const void* px  = d_in[0];  const void* pei = d_in[1];  const void* ppos = d_in[2];
    const void* pemb = d_in[3]; const void* pgW = d_in[4];  const void* pgB  = d_in[5];
    const void* pm1W = d_in[6]; const void* pm1B = d_in[7]; const void* pm2W = d_in[8];
    const void* pm2B = d_in[9]; const void* pm3W = d_in[10]; const void* pm3B = d_in[11];
    const void* plW = d_in[12]; const void* plB = d_in[13];
    {
        int c2048 = 0, c64 = 0, c32 = 0;
        for (int i = 0; i < n_in; i++) {
            int s = in_sizes[i]; const void* p = d_in[i];
            switch (s) {
                case 768:   px = p; break;
                case 49152: pei = p; break;
                case 8192:  ppos = p; break;
                case 3232:  pemb = p; break;
                case 2048:  if (c2048 == 0) pgW = p; else if (c2048 == 1) pm1W = p; else pm2W = p; c2048++; break;
                case 64:    if (c64 == 0) pgB = p; else plW = p; c64++; break;
                case 32:    if (c32 == 0) pm1B = p; else if (c32 == 1) pm2B = p; else pm3B = p; c32++; break;
                case 1056:  pm3W = p; break;
                case 1:     plB = p; break;
                default: break;
            }
        }
    }

    char* ws = (char*)d_ws;
    size_t off = 0;
    auto alloc = [&](size_t bytes) -> void* {
        void* pp = ws + off;
        off += (bytes + 255) & ~(size_t)255;
        return pp;
    };
    int*   cell    = (int*)alloc(NCELL * 4);       // counts -> pairIdx in-place
    int*   pcur    = (int*)alloc(NCELL * 4);       // path counts -> local scan -> local ends
    int*   rowlen  = (int*)alloc(NN * 4);
    int*   row_ptr = (int*)alloc((NN + 1) * 4);
    int*   col_idx = (int*)alloc(NE * 4);
    float* cntv    = (float*)alloc(NE * 4);
    int*   pr_row  = (int*)alloc(NE * 4);
    int*   cursor  = (int*)alloc(NN * 4);
    float* dinv    = (float*)alloc(NN * 4);
    float* h       = (float*)alloc(NN * 32 * 4);
    float* bufA    = (float*)alloc(NN * 32 * 4);
    float* bufB    = (float*)alloc(NN * 32 * 4);
    float* xep     = (float*)alloc(NE * 32 * 4);
    float* mulp    = (float*)alloc(NE * 32 * 4);
    float* stats   = (float*)alloc(66 * 4);
    float* nrm     = (float*)alloc(64 * 4);
    float* gwf     = (float*)alloc(2048 * 4);
    float* gbf     = (float*)alloc(64 * 4);
    float* w1f     = (float*)alloc(2048 * 4);
    float* b1f     = (float*)alloc(32 * 4);
    float* w2f     = (float*)alloc(2048 * 4);
    float* b2f     = (float*)alloc(32 * 4);
    float* w3q     = (float*)alloc(32 * 36 * 4);
    float* linf    = (float*)alloc(64 * 4);
    float* linb    = (float*)alloc(4);
    int*   mode    = (int*)alloc(4);
    int*   dcs     = (int*)alloc(8 * 4);
    int*   bsum    = (int*)alloc(NBLK * 4);
    int*   boff    = (int*)alloc(NBLK * 4);
    size_t remain = (ws_size > off) ? (ws_size - off) : 0;
    int cap = (int)(remain / 8);
    if (cap > (1 << 20)) cap = (1 << 20);
    int2*  paths2  = (int2*)alloc((size_t)cap * 8);

    k_setup<<<2 * NBLK + 2, 256, 0, stream>>>(pgW, pgB, pm1W, pm1B, pm2W, pm2B, pm3W, pm3B, plW, plB,
                                              pemb, cell, pcur, stats, cursor, rowlen, dcs, mode,
                                              gwf, gbf, w1f, b1f, w2f, b2f, w3q, linf, linb);
    k_scatter<<<96, 256, 0, stream>>>((const int*)pei, cell, rowlen);
    k_scan<<<1, NN, 0, stream>>>(rowlen, row_ptr, dinv);
    k_fillpar<<<NBLK, 256, 0, stream>>>(cell, row_ptr, cursor, col_idx, cntv, pr_row);
    // path machinery: wave per e1 edge
    k_cnt<<<NE / 4, 256, 0, stream>>>(row_ptr, col_idx, pr_row, pcur);
    k_scan1<<<NBLK, 256, 0, stream>>>(pcur, bsum);
    k_scan2<<<1, 768, 0, stream>>>(bsum, boff);
    k_join2<<<NE / 4, 256, 0, stream>>>(row_ptr, col_idx, pr_row, pcur, boff, paths2, cap);
    // GCN chain
    k_matw0<<<96, 256, 0, stream>>>((const int*)px, pemb, mode, gwf, bufA);
    k_agg<<<96, 256, 0, stream>>>(bufA, row_ptr, col_idx, dinv, gbf, 0, bufB);
    k_norm<<<1, 1024, 0, stream>>>(bufB, h);
    k_matw<<<96, 256, 0, stream>>>(h, gwf, bufA);
    k_agg<<<96, 256, 0, stream>>>(bufA, row_ptr, col_idx, dinv, gbf, 1, bufB);
    k_norm<<<1, 1024, 0, stream>>>(bufB, h);
    k_edgemlp<<<NE / 8, 256, 0, stream>>>(h, row_ptr, col_idx, pr_row, cntv, w1f, b1f, w2f, b2f, xep, mulp);
    // fused big pass + output
    k_big<<<NBLK, 256, 0, stream>>>(pcur, boff, paths2, cell, (const float4*)xep, (const float4*)mulp,
                                    w3q, stats, &dcs[0], nrm, cap);
    k_out<<<NPOS / 4, 256, 0, stream>>>((const int*)ppos, pcur, boff, paths2, cell, xep, mulp, h,
                                        w3q, nrm, linf, linb, mode, cap, d_out);
}